// Round 8
// baseline (132.933 us; speedup 1.0000x reference)
//
#include <hip/hip_runtime.h>
#include <math.h>

#define BB 16
#define NN 4096
#define CC 512
#define C2 256
#define CHUNKS 64
#define RPC (NN/CHUNKS)   // 64 rows per chunk
#define NW (CC*C2)        // elems per weight matrix = 131072

typedef float  f4v __attribute__((ext_vector_type(4)));
typedef _Float16 h8v __attribute__((ext_vector_type(8)));
typedef float    f8v __attribute__((ext_vector_type(8)));
typedef unsigned short ushort;
typedef unsigned int   uint;

__device__ __forceinline__ float sigmoidf_(float z){ return 1.0f/(1.0f + __expf(-z)); }
__device__ __forceinline__ float dot8_(float4 a0, float4 a1, float4 b0, float4 b1){
    return a0.x*b0.x + a0.y*b0.y + a0.z*b0.z + a0.w*b0.w
         + a1.x*b1.x + a1.y*b1.y + a1.z*b1.z + a1.w*b1.w;
}
__device__ __forceinline__ ushort f2bf(float f){
    uint u = __float_as_uint(f);
    return (ushort)((u + 0x7FFFu + ((u >> 16) & 1u)) >> 16);   // RNE
}
__device__ __forceinline__ float2 bfpair(uint v){
    return make_float2(__uint_as_float(v << 16), __uint_as_float(v & 0xFFFF0000u));
}

// ---------- K1: grid = BB*CHUNKS stats-blocks + 64 weight-convert blocks.
// Single pass over x, unnormalized exp (|logit| < ~3 for this data).
// Lane owns contiguous channels [lane*8, lane*8+8). Optionally emits fp16 echo of x.
template<int ECHO>
__global__ __launch_bounds__(256) void k_stats(const float* __restrict__ x,
        const float* __restrict__ wq,
        const float* __restrict__ Wv, const float* __restrict__ Wz,
        const float* __restrict__ Wq2, const float* __restrict__ Wv2,
        float* __restrict__ part_w, float* __restrict__ part_g,
        float* __restrict__ part_d, ushort* __restrict__ wbf,
        _Float16* __restrict__ echo)
{
    const int t = threadIdx.x, lane = t & 63, wv = t >> 6;

    if (blockIdx.x >= BB*CHUNKS) {
        // ---- weight conversion: 64 blocks x 256 threads x 32 elems
        const int idx = blockIdx.x - BB*CHUNKS;          // 0..63
        const int mat = idx >> 4;
        const float* src = (mat == 0) ? Wv : (mat == 1) ? Wz : (mat == 2) ? Wq2 : Wv2;
        const int boff = (idx & 15) * 8192;
        ushort* dst = wbf + (long)mat*NW + boff;
        const float* s = src + boff;
        #pragma unroll 8
        for (int e = 0; e < 32; ++e)
            dst[t + e*256] = f2bf(s[t + e*256]);
        return;
    }

    const int b = blockIdx.x / CHUNKS;
    const int k = blockIdx.x % CHUNKS;
    __shared__ float rw[4][CC];
    __shared__ float rg[4][CC];
    __shared__ float rd[4];
    const long rowbase = (long)b*NN + (long)k*RPC;
    const long base = rowbase * CC;

    float4 w0 = *(const float4*)(wq + lane*8);
    float4 w1 = *(const float4*)(wq + lane*8 + 4);
    float4 aw0={0,0,0,0}, aw1={0,0,0,0}, ag0={0,0,0,0}, ag1={0,0,0,0};
    float den = 0.f;

    for (int i = 0; i < RPC/8; ++i) {            // 16 rows/wave, 2 per iter (ILP)
        const int r0 = wv*(RPC/4) + 2*i;
        const float* xr0 = x + base + (long)r0*CC;
        const float* xr1 = xr0 + CC;
        float4 a0 = *(const float4*)(xr0 + lane*8);
        float4 a1 = *(const float4*)(xr0 + lane*8 + 4);
        float4 b0 = *(const float4*)(xr1 + lane*8);
        float4 b1 = *(const float4*)(xr1 + lane*8 + 4);
        float da = dot8_(a0, a1, w0, w1);
        float db = dot8_(b0, b1, w0, w1);
        #pragma unroll
        for (int off = 32; off; off >>= 1) {
            da += __shfl_xor(da, off);
            db += __shfl_xor(db, off);
        }
        if (ECHO) {
            h8v ha, hb;
            ha[0]=(_Float16)a0.x; ha[1]=(_Float16)a0.y; ha[2]=(_Float16)a0.z; ha[3]=(_Float16)a0.w;
            ha[4]=(_Float16)a1.x; ha[5]=(_Float16)a1.y; ha[6]=(_Float16)a1.z; ha[7]=(_Float16)a1.w;
            hb[0]=(_Float16)b0.x; hb[1]=(_Float16)b0.y; hb[2]=(_Float16)b0.z; hb[3]=(_Float16)b0.w;
            hb[4]=(_Float16)b1.x; hb[5]=(_Float16)b1.y; hb[6]=(_Float16)b1.z; hb[7]=(_Float16)b1.w;
            *(h8v*)(echo + (rowbase + r0)*CC + lane*8)     = ha;
            *(h8v*)(echo + (rowbase + r0 + 1)*CC + lane*8) = hb;
        }
        const float ea = __expf(da);
        const float eb = __expf(db);
        den += ea + eb;
        aw0.x = fmaf(ea,a0.x,fmaf(eb,b0.x,aw0.x)); aw0.y = fmaf(ea,a0.y,fmaf(eb,b0.y,aw0.y));
        aw0.z = fmaf(ea,a0.z,fmaf(eb,b0.z,aw0.z)); aw0.w = fmaf(ea,a0.w,fmaf(eb,b0.w,aw0.w));
        aw1.x = fmaf(ea,a1.x,fmaf(eb,b1.x,aw1.x)); aw1.y = fmaf(ea,a1.y,fmaf(eb,b1.y,aw1.y));
        aw1.z = fmaf(ea,a1.z,fmaf(eb,b1.z,aw1.z)); aw1.w = fmaf(ea,a1.w,fmaf(eb,b1.w,aw1.w));
        ag0.x += a0.x+b0.x; ag0.y += a0.y+b0.y; ag0.z += a0.z+b0.z; ag0.w += a0.w+b0.w;
        ag1.x += a1.x+b1.x; ag1.y += a1.y+b1.y; ag1.z += a1.z+b1.z; ag1.w += a1.w+b1.w;
    }
    *(float4*)&rw[wv][lane*8]     = aw0;
    *(float4*)&rw[wv][lane*8 + 4] = aw1;
    *(float4*)&rg[wv][lane*8]     = ag0;
    *(float4*)&rg[wv][lane*8 + 4] = ag1;
    if (lane == 0) rd[wv] = den;
    __syncthreads();

    const long o = (long)(b*CHUNKS + k)*CC;
    part_w[o + t]       = rw[0][t]+rw[1][t]+rw[2][t]+rw[3][t];
    part_w[o + t + 256] = rw[0][t+256]+rw[1][t+256]+rw[2][t+256]+rw[3][t+256];
    part_g[o + t]       = rg[0][t]+rg[1][t]+rg[2][t]+rg[3][t];
    part_g[o + t + 256] = rg[0][t+256]+rg[1][t+256]+rg[2][t+256]+rg[3][t+256];
    if (t == 0) part_d[b*CHUNKS + k] = rd[0]+rd[1]+rd[2]+rd[3];
}

// ---------- K2: whole per-batch chain, one block per batch, 512 threads, bf16-pair loads.
__global__ __launch_bounds__(512) void k_chain(
    const float* __restrict__ part_w, const float* __restrict__ part_g,
    const float* __restrict__ part_d,
    const ushort* __restrict__ wbf,
    const float* __restrict__ bv,  const float* __restrict__ bz,
    const float* __restrict__ lng, const float* __restrict__ lnb,
    const float* __restrict__ bq,  const float* __restrict__ bv2,
    float* __restrict__ cw, float* __restrict__ veff, float* __restrict__ constb)
{
    const int b = blockIdx.x, t = threadIdx.x, lane = t & 63, w = t >> 6;  // 8 waves
    const ushort* Wvb  = wbf;            // (512,256)
    const ushort* Wzb  = wbf + NW;       // (256,512)
    const ushort* Wqb  = wbf + 2*NW;     // (512,256)
    const ushort* Wv2b = wbf + 3*NW;     // (512,256)
    __shared__ float s_a[CC];    // xbar -> gco
    __shared__ float s_b[CC];    // gap  -> qn (lower half)
    __shared__ float s_c[CC];    // cw
    __shared__ float s_m[C2];    // mid
    __shared__ float s_g1[1024]; // GEMV partial scratch
    __shared__ float s_r[16];

    // ---- combine (nt loads: partials single-use)
    {
        const float* pwp = part_w + (long)b*CHUNKS*CC + t;
        const float* pgp = part_g + (long)b*CHUNKS*CC + t;
        float pw = 0.f, pg = 0.f;
        #pragma unroll 8
        for (int k = 0; k < CHUNKS; ++k) {
            pw += __builtin_nontemporal_load(pwp + (long)k*CC);
            pg += __builtin_nontemporal_load(pgp + (long)k*CC);
        }
        const float* pd = part_d + b*CHUNKS;
        float den = 0.f;
        #pragma unroll 8
        for (int k = 0; k < CHUNKS; ++k) den += pd[k];
        s_a[t] = pw / den;
        s_b[t] = pg;
    }
    __syncthreads();

    // ---- G1: mid[d] = xbar . Wv[:,d] + bv[d]  (lane owns d-pair; 4 c-quarters)
    {
        const int pr = t & 127, cq = t >> 7;
        const ushort* wp = Wvb + (long)(cq*128)*C2 + 2*pr;
        const float* xp = s_a + cq*128;
        float ax=0, ay=0, bx=0, by=0;
        #pragma unroll 8
        for (int c = 0; c < 128; c += 2) {
            uint u0 = *(const uint*)(wp + (long)(c  )*C2);
            uint u1 = *(const uint*)(wp + (long)(c+1)*C2);
            float2 p0 = bfpair(u0), p1 = bfpair(u1);
            ax = fmaf(xp[c],   p0.x, ax); ay = fmaf(xp[c],   p0.y, ay);
            bx = fmaf(xp[c+1], p1.x, bx); by = fmaf(xp[c+1], p1.y, by);
        }
        s_g1[cq*256 + pr*2]     = ax + bx;
        s_g1[cq*256 + pr*2 + 1] = ay + by;
    }
    __syncthreads();
    if (t < 256) s_m[t] = s_g1[t] + s_g1[256+t] + s_g1[512+t] + s_g1[768+t] + bv[t];
    __syncthreads();

    // ---- G2: z[c] = mid . Wz[:,c] + bz[c]
    {
        const int cp = t & 255, dh = t >> 8;
        const ushort* wp = Wzb + (long)(dh*128)*CC + 2*cp;
        const float* mp = s_m + dh*128;
        float ax=0, ay=0, bx=0, by=0;
        #pragma unroll 8
        for (int d = 0; d < 128; d += 2) {
            uint u0 = *(const uint*)(wp + (long)(d  )*CC);
            uint u1 = *(const uint*)(wp + (long)(d+1)*CC);
            float2 p0 = bfpair(u0), p1 = bfpair(u1);
            ax = fmaf(mp[d],   p0.x, ax); ay = fmaf(mp[d],   p0.y, ay);
            bx = fmaf(mp[d+1], p1.x, bx); by = fmaf(mp[d+1], p1.y, by);
        }
        s_g1[dh*512 + cp*2]     = ax + bx;
        s_g1[dh*512 + cp*2 + 1] = ay + by;
    }
    __syncthreads();
    float zt = s_g1[t] + s_g1[512 + t] + bz[t];

    // ---- LN over 512 + sigmoid -> cw ; gco = cw*gap/N
    {
        float sum = zt, sq = zt*zt;
        #pragma unroll
        for (int off = 32; off; off >>= 1) { sum += __shfl_xor(sum, off); sq += __shfl_xor(sq, off); }
        if (lane == 0) { s_r[w] = sum; s_r[8+w] = sq; }
        __syncthreads();
        sum = 0.f; sq = 0.f;
        #pragma unroll
        for (int i = 0; i < 8; ++i) { sum += s_r[i]; sq += s_r[8+i]; }
        const float mean = sum * (1.f/CC);
        const float var  = sq  * (1.f/CC) - mean*mean;
        const float rstd = rsqrtf(var + 1e-3f);
        const float cwt = sigmoidf_((zt - mean)*rstd*lng[t] + lnb[t]);
        cw[b*CC + t] = cwt;
        __syncthreads();
        s_c[t] = cwt;
        s_a[t] = cwt * s_b[t] * (1.f/NN);   // gco
    }
    __syncthreads();

    // ---- G3: qraw[d] = gco . Wq[:,d] + bq[d]
    {
        const int pr = t & 127, cq = t >> 7;
        const ushort* wp = Wqb + (long)(cq*128)*C2 + 2*pr;
        const float* xp = s_a + cq*128;
        float ax=0, ay=0, bx=0, by=0;
        #pragma unroll 8
        for (int c = 0; c < 128; c += 2) {
            uint u0 = *(const uint*)(wp + (long)(c  )*C2);
            uint u1 = *(const uint*)(wp + (long)(c+1)*C2);
            float2 p0 = bfpair(u0), p1 = bfpair(u1);
            ax = fmaf(xp[c],   p0.x, ax); ay = fmaf(xp[c],   p0.y, ay);
            bx = fmaf(xp[c+1], p1.x, bx); by = fmaf(xp[c+1], p1.y, by);
        }
        s_g1[cq*256 + pr*2]     = ax + bx;
        s_g1[cq*256 + pr*2 + 1] = ay + by;
    }
    __syncthreads();

    // ---- softmax over 256 + constb
    float qv = 0.f;
    if (t < 256) qv = s_g1[t] + s_g1[256+t] + s_g1[512+t] + s_g1[768+t] + bq[t];
    {
        float mx = (t < 256) ? qv : -3.4e38f;
        #pragma unroll
        for (int off = 32; off; off >>= 1) mx = fmaxf(mx, __shfl_xor(mx, off));
        if (lane == 0) s_r[w] = mx;
        __syncthreads();
        mx = s_r[0];
        #pragma unroll
        for (int i = 1; i < 8; ++i) mx = fmaxf(mx, s_r[i]);
        float e = (t < 256) ? __expf(qv - mx) : 0.f;
        float se = e;
        #pragma unroll
        for (int off = 32; off; off >>= 1) se += __shfl_xor(se, off);
        __syncthreads();
        if (lane == 0) s_r[8+w] = se;
        __syncthreads();
        se = 0.f;
        #pragma unroll
        for (int i = 0; i < 8; ++i) se += s_r[8+i];
        const float qn = e / se;
        float cb = (t < 256) ? qn * bv2[t] : 0.f;
        #pragma unroll
        for (int off = 32; off; off >>= 1) cb += __shfl_xor(cb, off);
        if (lane == 0) s_r[w] = cb;
        __syncthreads();
        if (t < 256) s_b[t] = qn;
        if (t == 0) {
            float c_ = 0.f;
            #pragma unroll
            for (int i = 0; i < 8; ++i) c_ += s_r[i];
            constb[b] = c_;
        }
    }
    __syncthreads();

    // ---- veff[c] = cw[c] * (Wv2[c,:] . qn)
    {
        const int sub = lane & 15;
        float4 q0 = *(const float4*)(s_b + sub*16 + 0);
        float4 q1 = *(const float4*)(s_b + sub*16 + 4);
        float4 q2 = *(const float4*)(s_b + sub*16 + 8);
        float4 q3 = *(const float4*)(s_b + sub*16 + 12);
        for (int it = 0; it < 16; ++it) {
            const int c = (it*8 + w)*4 + (lane >> 4);
            const uint4* wr = (const uint4*)(Wv2b + (long)c*C2) + sub*2;
            uint4 u0 = wr[0], u1 = wr[1];
            float2 p;
            float d = 0.f;
            p = bfpair(u0.x); d += p.x*q0.x + p.y*q0.y;
            p = bfpair(u0.y); d += p.x*q0.z + p.y*q0.w;
            p = bfpair(u0.z); d += p.x*q1.x + p.y*q1.y;
            p = bfpair(u0.w); d += p.x*q1.z + p.y*q1.w;
            p = bfpair(u1.x); d += p.x*q2.x + p.y*q2.y;
            p = bfpair(u1.y); d += p.x*q2.z + p.y*q2.w;
            p = bfpair(u1.z); d += p.x*q3.x + p.y*q3.y;
            p = bfpair(u1.w); d += p.x*q3.z + p.y*q3.w;
            #pragma unroll
            for (int off = 8; off; off >>= 1) d += __shfl_xor(d, off);
            if (sub == 0) veff[b*CC + c] = s_c[c] * d;
        }
    }
}

// ---------- K3a (echo path): out = sigmoid(echo.veff + cb) * cw * echo, fp16 echo reads.
// Lane owns channels [lane*8, lane*8+8); wave does 4 rows; block 16 rows (same b).
__global__ __launch_bounds__(256) void k_final_echo(const _Float16* __restrict__ echo,
        const float* __restrict__ cw, const float* __restrict__ veff,
        const float* __restrict__ constb, float* __restrict__ out)
{
    const int lane = threadIdx.x & 63;
    const int wv   = threadIdx.x >> 6;
    const long row0 = (long)blockIdx.x * 16 + wv*4;
    const int b = (int)(row0 >> 12);
    const float* vb = veff + b*CC + lane*8;
    float4 v0 = *(const float4*)(vb);
    float4 v1 = *(const float4*)(vb + 4);
    const float* cb = cw + b*CC + lane*8;
    float4 c0 = *(const float4*)(cb);
    float4 c1 = *(const float4*)(cb + 4);
    const _Float16* e0 = echo + row0*CC + lane*8;

    f8v x0 = __builtin_convertvector(*(const h8v*)(e0),        f8v);
    f8v x1 = __builtin_convertvector(*(const h8v*)(e0 + CC),   f8v);
    f8v x2 = __builtin_convertvector(*(const h8v*)(e0 + 2*CC), f8v);
    f8v x3 = __builtin_convertvector(*(const h8v*)(e0 + 3*CC), f8v);

    float d0 = x0[0]*v0.x + x0[1]*v0.y + x0[2]*v0.z + x0[3]*v0.w
             + x0[4]*v1.x + x0[5]*v1.y + x0[6]*v1.z + x0[7]*v1.w;
    float d1 = x1[0]*v0.x + x1[1]*v0.y + x1[2]*v0.z + x1[3]*v0.w
             + x1[4]*v1.x + x1[5]*v1.y + x1[6]*v1.z + x1[7]*v1.w;
    float d2 = x2[0]*v0.x + x2[1]*v0.y + x2[2]*v0.z + x2[3]*v0.w
             + x2[4]*v1.x + x2[5]*v1.y + x2[6]*v1.z + x2[7]*v1.w;
    float d3 = x3[0]*v0.x + x3[1]*v0.y + x3[2]*v0.z + x3[3]*v0.w
             + x3[4]*v1.x + x3[5]*v1.y + x3[6]*v1.z + x3[7]*v1.w;
    #pragma unroll
    for (int off = 32; off; off >>= 1) {
        d0 += __shfl_xor(d0, off);
        d1 += __shfl_xor(d1, off);
        d2 += __shfl_xor(d2, off);
        d3 += __shfl_xor(d3, off);
    }
    const float cbb = constb[b];
    const float s0 = sigmoidf_(d0 + cbb);
    const float s1 = sigmoidf_(d1 + cbb);
    const float s2 = sigmoidf_(d2 + cbb);
    const float s3 = sigmoidf_(d3 + cbb);
    float* op = out + row0*CC + lane*8;
    f4v o;
    o = (f4v){ s0*c0.x*x0[0], s0*c0.y*x0[1], s0*c0.z*x0[2], s0*c0.w*x0[3] };
    __builtin_nontemporal_store(o, (f4v*)(op));
    o = (f4v){ s0*c1.x*x0[4], s0*c1.y*x0[5], s0*c1.z*x0[6], s0*c1.w*x0[7] };
    __builtin_nontemporal_store(o, (f4v*)(op + 4));
    o = (f4v){ s1*c0.x*x1[0], s1*c0.y*x1[1], s1*c0.z*x1[2], s1*c0.w*x1[3] };
    __builtin_nontemporal_store(o, (f4v*)(op + CC));
    o = (f4v){ s1*c1.x*x1[4], s1*c1.y*x1[5], s1*c1.z*x1[6], s1*c1.w*x1[7] };
    __builtin_nontemporal_store(o, (f4v*)(op + CC + 4));
    o = (f4v){ s2*c0.x*x2[0], s2*c0.y*x2[1], s2*c0.z*x2[2], s2*c0.w*x2[3] };
    __builtin_nontemporal_store(o, (f4v*)(op + 2*CC));
    o = (f4v){ s2*c1.x*x2[4], s2*c1.y*x2[5], s2*c1.z*x2[6], s2*c1.w*x2[7] };
    __builtin_nontemporal_store(o, (f4v*)(op + 2*CC + 4));
    o = (f4v){ s3*c0.x*x3[0], s3*c0.y*x3[1], s3*c0.z*x3[2], s3*c0.w*x3[3] };
    __builtin_nontemporal_store(o, (f4v*)(op + 3*CC));
    o = (f4v){ s3*c1.x*x3[4], s3*c1.y*x3[5], s3*c1.z*x3[6], s3*c1.w*x3[7] };
    __builtin_nontemporal_store(o, (f4v*)(op + 3*CC + 4));
}

// ---------- K3b (fallback, fp32 x): round-7 version
__global__ __launch_bounds__(256) void k_final_f32(const float* __restrict__ x,
        const float* __restrict__ cw, const float* __restrict__ veff,
        const float* __restrict__ constb, float* __restrict__ out)
{
    const int lane = threadIdx.x & 63;
    const int wv   = threadIdx.x >> 6;
    const long row0 = (long)blockIdx.x * 8 + wv*2;
    const int b = (int)(row0 >> 12);
    const float* vb = veff + b*CC;
    float4 v0 = *(const float4*)(vb + lane*4);
    float4 v1 = *(const float4*)(vb + 256 + lane*4);
    const float* cb = cw + b*CC;
    float4 c0 = *(const float4*)(cb + lane*4);
    float4 c1 = *(const float4*)(cb + 256 + lane*4);
    const float* xr0 = x + row0 * CC;
    float4 a0 = *(const float4*)(xr0 + lane*4);
    float4 a1 = *(const float4*)(xr0 + 256 + lane*4);
    float4 b0 = *(const float4*)(xr0 + CC + lane*4);
    float4 b1 = *(const float4*)(xr0 + CC + 256 + lane*4);
    float d0 = dot8_(a0, a1, v0, v1);
    float d1 = dot8_(b0, b1, v0, v1);
    #pragma unroll
    for (int off = 32; off; off >>= 1) {
        d0 += __shfl_xor(d0, off);
        d1 += __shfl_xor(d1, off);
    }
    const float cbb = constb[b];
    const float sw0 = sigmoidf_(d0 + cbb);
    const float sw1 = sigmoidf_(d1 + cbb);
    f4v o0 = { sw0*c0.x*a0.x, sw0*c0.y*a0.y, sw0*c0.z*a0.z, sw0*c0.w*a0.w };
    f4v o1 = { sw0*c1.x*a1.x, sw0*c1.y*a1.y, sw0*c1.z*a1.z, sw0*c1.w*a1.w };
    f4v o2 = { sw1*c0.x*b0.x, sw1*c0.y*b0.y, sw1*c0.z*b0.z, sw1*c0.w*b0.w };
    f4v o3 = { sw1*c1.x*b1.x, sw1*c1.y*b1.y, sw1*c1.z*b1.z, sw1*c1.w*b1.w };
    __builtin_nontemporal_store(o0, (f4v*)(out + row0*CC + lane*4));
    __builtin_nontemporal_store(o1, (f4v*)(out + row0*CC + 256 + lane*4));
    __builtin_nontemporal_store(o2, (f4v*)(out + row0*CC + CC + lane*4));
    __builtin_nontemporal_store(o3, (f4v*)(out + row0*CC + CC + 256 + lane*4));
}

extern "C" void kernel_launch(void* const* d_in, const int* in_sizes, int n_in,
                              void* d_out, int out_size, void* d_ws, size_t ws_size,
                              hipStream_t stream)
{
    const float* x       = (const float*)d_in[0];
    const float* ch_wv_w = (const float*)d_in[1];
    const float* ch_wv_b = (const float*)d_in[2];
    const float* ch_wq_w = (const float*)d_in[3];
    // d_in[4] = ch_wq_b unused (softmax shift-invariant)
    const float* ch_wz_w = (const float*)d_in[5];
    const float* ch_wz_b = (const float*)d_in[6];
    const float* ln_g    = (const float*)d_in[7];
    const float* ln_b    = (const float*)d_in[8];
    const float* sp_wv_w = (const float*)d_in[9];
    const float* sp_wv_b = (const float*)d_in[10];
    const float* sp_wq_w = (const float*)d_in[11];
    const float* sp_wq_b = (const float*)d_in[12];
    float* out = (float*)d_out;

    const size_t echo_bytes = (size_t)BB*NN*CC*sizeof(_Float16);   // 64 MiB
    const size_t rest_floats = (size_t)BB*CHUNKS*CC*2 + BB*CHUNKS + BB*CC*2 + BB + 16;
    const size_t rest_bytes  = rest_floats*4 + (size_t)4*NW*sizeof(ushort);
    const bool use_echo = ws_size >= echo_bytes + rest_bytes;

    _Float16* echo = (_Float16*)d_ws;
    float* ws = use_echo ? (float*)((char*)d_ws + echo_bytes) : (float*)d_ws;
    float* part_w  = ws;
    float* part_g  = part_w + BB*CHUNKS*CC;
    float* part_d  = part_g + BB*CHUNKS*CC;
    float* cw      = part_d + BB*CHUNKS;
    float* veff    = cw + BB*CC;
    float* constb  = veff + BB*CC;
    ushort* wbf    = (ushort*)(constb + BB + 15);

    if (use_echo) {
        k_stats<1><<<BB*CHUNKS + 64, 256, 0, stream>>>(x, ch_wq_w,
                                                ch_wv_w, ch_wz_w, sp_wq_w, sp_wv_w,
                                                part_w, part_g, part_d, wbf, echo);
    } else {
        k_stats<0><<<BB*CHUNKS + 64, 256, 0, stream>>>(x, ch_wq_w,
                                                ch_wv_w, ch_wz_w, sp_wq_w, sp_wv_w,
                                                part_w, part_g, part_d, wbf, echo);
    }
    k_chain<<<BB,  512, 0, stream>>>(part_w, part_g, part_d, wbf,
                                     ch_wv_b, ch_wz_b, ln_g, ln_b, sp_wq_b, sp_wv_b,
                                     cw, veff, constb);
    if (use_echo)
        k_final_echo<<<BB*NN/16, 256, 0, stream>>>(echo, cw, veff, constb, out);
    else
        k_final_f32 <<<BB*NN/8,  256, 0, stream>>>(x, cw, veff, constb, out);
}

// Round 9
// 88.076 us; speedup vs baseline: 1.5093x; 1.5093x over previous
//
#include <hip/hip_runtime.h>
#include <math.h>

#define BB 16
#define NN 4096
#define CC 512
#define C2 256
#define CHUNKS 64
#define RPC (NN/CHUNKS)   // 64 rows per chunk
#define NW (CC*C2)        // elems per weight matrix = 131072

typedef float  f4v __attribute__((ext_vector_type(4)));
typedef unsigned short ushort;
typedef unsigned int   uint;

__device__ __forceinline__ float sigmoidf_(float z){ return 1.0f/(1.0f + __expf(-z)); }
__device__ __forceinline__ float dot8_(float4 a0, float4 a1, float4 b0, float4 b1){
    return a0.x*b0.x + a0.y*b0.y + a0.z*b0.z + a0.w*b0.w
         + a1.x*b1.x + a1.y*b1.y + a1.z*b1.z + a1.w*b1.w;
}
__device__ __forceinline__ ushort f2bf(float f){
    uint u = __float_as_uint(f);
    return (ushort)((u + 0x7FFFu + ((u >> 16) & 1u)) >> 16);   // RNE
}
__device__ __forceinline__ float2 bfpair(uint v){   // (low-addr elem, high-addr elem)
    return make_float2(__uint_as_float(v << 16), __uint_as_float(v & 0xFFFF0000u));
}

// ---------- K1: grid = BB*CHUNKS stats-blocks + 64 weight-convert blocks.
// stats: single pass over x, unnormalized exp (|logit| < ~3 for this data),
// 2-row ILP: two independent dot/shfl/exp chains per iteration.
__global__ __launch_bounds__(256) void k_stats(const float* __restrict__ x,
        const float* __restrict__ wq,
        const float* __restrict__ Wv, const float* __restrict__ Wz,
        const float* __restrict__ Wq2, const float* __restrict__ Wv2,
        float* __restrict__ part_w, float* __restrict__ part_g,
        float* __restrict__ part_d, ushort* __restrict__ wbf)
{
    const int t = threadIdx.x, lane = t & 63, wv = t >> 6;

    if (blockIdx.x >= BB*CHUNKS) {
        // ---- weight conversion: 64 blocks x 256 threads x 32 elems
        const int idx = blockIdx.x - BB*CHUNKS;          // 0..63
        const int mat = idx >> 4;
        const float* src = (mat == 0) ? Wv : (mat == 1) ? Wz : (mat == 2) ? Wq2 : Wv2;
        const int boff = (idx & 15) * 8192;
        ushort* dst = wbf + (long)mat*NW + boff;
        const float* s = src + boff;
        #pragma unroll 8
        for (int e = 0; e < 32; ++e)
            dst[t + e*256] = f2bf(s[t + e*256]);
        return;
    }

    const int b = blockIdx.x / CHUNKS;
    const int k = blockIdx.x % CHUNKS;
    __shared__ float rw[4][CC];
    __shared__ float rg[4][CC];
    __shared__ float rd[4];
    const long base = ((long)b*NN + (long)k*RPC) * CC;

    float4 w0 = *(const float4*)(wq + lane*4);
    float4 w1 = *(const float4*)(wq + 256 + lane*4);
    float4 aw0={0,0,0,0}, aw1={0,0,0,0}, ag0={0,0,0,0}, ag1={0,0,0,0};
    float den = 0.f;

    for (int i = 0; i < RPC/8; ++i) {            // 16 rows/wave, 2 per iter
        const int r0 = wv*(RPC/4) + 2*i;
        const float* xr0 = x + base + (long)r0*CC;
        const float* xr1 = xr0 + CC;
        float4 a0 = *(const float4*)(xr0 + lane*4);
        float4 a1 = *(const float4*)(xr0 + 256 + lane*4);
        float4 b0 = *(const float4*)(xr1 + lane*4);
        float4 b1 = *(const float4*)(xr1 + 256 + lane*4);
        float da = dot8_(a0, a1, w0, w1);
        float db = dot8_(b0, b1, w0, w1);
        #pragma unroll
        for (int off = 32; off; off >>= 1) {     // two chains interleave
            da += __shfl_xor(da, off);
            db += __shfl_xor(db, off);
        }
        const float ea = __expf(da);
        const float eb = __expf(db);
        den += ea + eb;
        aw0.x = fmaf(ea,a0.x,fmaf(eb,b0.x,aw0.x)); aw0.y = fmaf(ea,a0.y,fmaf(eb,b0.y,aw0.y));
        aw0.z = fmaf(ea,a0.z,fmaf(eb,b0.z,aw0.z)); aw0.w = fmaf(ea,a0.w,fmaf(eb,b0.w,aw0.w));
        aw1.x = fmaf(ea,a1.x,fmaf(eb,b1.x,aw1.x)); aw1.y = fmaf(ea,a1.y,fmaf(eb,b1.y,aw1.y));
        aw1.z = fmaf(ea,a1.z,fmaf(eb,b1.z,aw1.z)); aw1.w = fmaf(ea,a1.w,fmaf(eb,b1.w,aw1.w));
        ag0.x += a0.x+b0.x; ag0.y += a0.y+b0.y; ag0.z += a0.z+b0.z; ag0.w += a0.w+b0.w;
        ag1.x += a1.x+b1.x; ag1.y += a1.y+b1.y; ag1.z += a1.z+b1.z; ag1.w += a1.w+b1.w;
    }
    *(float4*)&rw[wv][lane*4]     = aw0;
    *(float4*)&rw[wv][256+lane*4] = aw1;
    *(float4*)&rg[wv][lane*4]     = ag0;
    *(float4*)&rg[wv][256+lane*4] = ag1;
    if (lane == 0) rd[wv] = den;
    __syncthreads();

    const long o = (long)(b*CHUNKS + k)*CC;
    part_w[o + t]       = rw[0][t]+rw[1][t]+rw[2][t]+rw[3][t];
    part_w[o + t + 256] = rw[0][t+256]+rw[1][t+256]+rw[2][t+256]+rw[3][t+256];
    part_g[o + t]       = rg[0][t]+rg[1][t]+rg[2][t]+rg[3][t];
    part_g[o + t + 256] = rg[0][t+256]+rg[1][t+256]+rg[2][t+256]+rg[3][t+256];
    if (t == 0) part_d[b*CHUNKS + k] = rd[0]+rd[1]+rd[2]+rd[3];
}

// ---------- K2: whole per-batch chain, one block per batch, 1024 threads (16 waves).
__global__ __launch_bounds__(1024) void k_chain(
    const float* __restrict__ part_w, const float* __restrict__ part_g,
    const float* __restrict__ part_d,
    const ushort* __restrict__ wbf,
    const float* __restrict__ bv,  const float* __restrict__ bz,
    const float* __restrict__ lng, const float* __restrict__ lnb,
    const float* __restrict__ bq,  const float* __restrict__ bv2,
    float* __restrict__ cw, float* __restrict__ veff, float* __restrict__ constb)
{
    const int b = blockIdx.x, t = threadIdx.x, lane = t & 63, w = t >> 6;  // 16 waves
    const ushort* Wvb  = wbf;            // (512,256)
    const ushort* Wzb  = wbf + NW;       // (256,512)
    const ushort* Wqb  = wbf + 2*NW;     // (512,256)
    const ushort* Wv2b = wbf + 3*NW;     // (512,256)
    __shared__ float s_a[CC];    // xbar -> gco
    __shared__ float s_b[CC];    // gap  -> qn (lower half)
    __shared__ float s_c[CC];    // cw
    __shared__ float s_m[C2];    // mid
    __shared__ float s_g[2048];  // GEMV partial scratch
    __shared__ float s_r[34];

    // ---- den = sum part_d
    if (t < 64) {
        float dv = part_d[b*CHUNKS + t];
        #pragma unroll
        for (int off = 32; off; off >>= 1) dv += __shfl_xor(dv, off);
        if (t == 0) s_r[32] = dv;
    }
    // ---- combine: two chunk-halves in parallel (nt loads: partials single-use)
    {
        const int c = t & 511, h = t >> 9;     // h in {0,1}
        const float* pwp = part_w + (long)b*CHUNKS*CC + (long)h*32*CC + c;
        const float* pgp = part_g + (long)b*CHUNKS*CC + (long)h*32*CC + c;
        float pw = 0.f, pg = 0.f;
        #pragma unroll 8
        for (int k = 0; k < 32; ++k) {
            pw += __builtin_nontemporal_load(pwp + (long)k*CC);
            pg += __builtin_nontemporal_load(pgp + (long)k*CC);
        }
        s_g[h*512 + c]        = pw;
        s_g[1024 + h*512 + c] = pg;
    }
    __syncthreads();
    if (t < 512) {
        const float inv = 1.f / s_r[32];
        s_a[t] = (s_g[t] + s_g[512+t]) * inv;       // xbar
        s_b[t] =  s_g[1024+t] + s_g[1536+t];        // gap
    }
    __syncthreads();

    // ---- G1: mid[d] = xbar . Wv[:,d] + bv[d]  (lane owns d-pair; 8 c-eighths)
    {
        const int pr = t & 127, cq = t >> 7;        // cq in [0,8)
        const ushort* wp = Wvb + (long)(cq*64)*C2 + 2*pr;
        const float* xp = s_a + cq*64;
        float ax=0, ay=0;
        #pragma unroll 8
        for (int c = 0; c < 64; ++c) {
            uint u = *(const uint*)(wp + (long)c*C2);
            float2 p = bfpair(u);
            ax = fmaf(xp[c], p.x, ax); ay = fmaf(xp[c], p.y, ay);
        }
        s_g[cq*256 + 2*pr]     = ax;
        s_g[cq*256 + 2*pr + 1] = ay;
    }
    __syncthreads();
    if (t < 256) {
        float s = bv[t];
        #pragma unroll
        for (int g = 0; g < 8; ++g) s += s_g[g*256 + t];
        s_m[t] = s;
    }
    __syncthreads();

    // ---- G2: z[c] = mid . Wz[:,c] + bz[c]  (lane owns c-pair; 4 d-quarters)
    {
        const int cp = t & 255, dq = t >> 8;        // dq in [0,4)
        const ushort* wp = Wzb + (long)(dq*64)*CC + 2*cp;
        const float* mp = s_m + dq*64;
        float ax=0, ay=0;
        #pragma unroll 8
        for (int d = 0; d < 64; ++d) {
            uint u = *(const uint*)(wp + (long)d*CC);
            float2 p = bfpair(u);
            ax = fmaf(mp[d], p.x, ax); ay = fmaf(mp[d], p.y, ay);
        }
        s_g[dq*512 + 2*cp]     = ax;
        s_g[dq*512 + 2*cp + 1] = ay;
    }
    __syncthreads();
    float zt = 0.f;
    if (t < 512) zt = s_g[t] + s_g[512+t] + s_g[1024+t] + s_g[1536+t] + bz[t];

    // ---- LN over 512 + sigmoid -> cw ; gco = cw*gap/N   (zt = 0 for t >= 512)
    {
        float sum = zt, sq = zt*zt;
        #pragma unroll
        for (int off = 32; off; off >>= 1) { sum += __shfl_xor(sum, off); sq += __shfl_xor(sq, off); }
        if (lane == 0) { s_r[w] = sum; s_r[16+w] = sq; }
        __syncthreads();
        sum = 0.f; sq = 0.f;
        #pragma unroll
        for (int i = 0; i < 16; ++i) { sum += s_r[i]; sq += s_r[16+i]; }
        const float mean = sum * (1.f/CC);
        const float var  = sq  * (1.f/CC) - mean*mean;
        const float rstd = rsqrtf(var + 1e-3f);
        if (t < 512) {
            const float cwt = sigmoidf_((zt - mean)*rstd*lng[t] + lnb[t]);
            cw[b*CC + t] = cwt;
            s_c[t] = cwt;
            s_a[t] = cwt * s_b[t] * (1.f/NN);   // gco
        }
    }
    __syncthreads();

    // ---- G3: qraw[d] = gco . Wq[:,d] + bq[d]  (same shape as G1)
    {
        const int pr = t & 127, cq = t >> 7;
        const ushort* wp = Wqb + (long)(cq*64)*C2 + 2*pr;
        const float* xp = s_a + cq*64;
        float ax=0, ay=0;
        #pragma unroll 8
        for (int c = 0; c < 64; ++c) {
            uint u = *(const uint*)(wp + (long)c*C2);
            float2 p = bfpair(u);
            ax = fmaf(xp[c], p.x, ax); ay = fmaf(xp[c], p.y, ay);
        }
        s_g[cq*256 + 2*pr]     = ax;
        s_g[cq*256 + 2*pr + 1] = ay;
    }
    __syncthreads();

    // ---- softmax over 256 + constb
    float qv = 0.f;
    if (t < 256) {
        qv = bq[t];
        #pragma unroll
        for (int g = 0; g < 8; ++g) qv += s_g[g*256 + t];
    }
    {
        float mx = (t < 256) ? qv : -3.4e38f;
        #pragma unroll
        for (int off = 32; off; off >>= 1) mx = fmaxf(mx, __shfl_xor(mx, off));
        if (lane == 0) s_r[w] = mx;
        __syncthreads();
        mx = s_r[0];
        #pragma unroll
        for (int i = 1; i < 16; ++i) mx = fmaxf(mx, s_r[i]);
        float e = (t < 256) ? __expf(qv - mx) : 0.f;
        float se = e;
        #pragma unroll
        for (int off = 32; off; off >>= 1) se += __shfl_xor(se, off);
        if (lane == 0) s_r[16+w] = se;
        __syncthreads();
        se = 0.f;
        #pragma unroll
        for (int i = 0; i < 16; ++i) se += s_r[16+i];
        const float qn = e / se;
        float cb = (t < 256) ? qn * bv2[t] : 0.f;
        #pragma unroll
        for (int off = 32; off; off >>= 1) cb += __shfl_xor(cb, off);
        __syncthreads();                 // all mx/se reads done before s_r reuse
        if (lane == 0) s_r[w] = cb;
        __syncthreads();
        if (t < 256) s_b[t] = qn;
        if (t == 0) {
            float c_ = 0.f;
            #pragma unroll
            for (int i = 0; i < 16; ++i) c_ += s_r[i];
            constb[b] = c_;
        }
    }
    __syncthreads();

    // ---- veff[c] = cw[c] * (Wv2[c,:] . qn)  — 16 lanes/row, uint4 = 8 bf16 per load
    {
        const int sub = lane & 15;
        float4 q0 = *(const float4*)(s_b + sub*16 + 0);
        float4 q1 = *(const float4*)(s_b + sub*16 + 4);
        float4 q2 = *(const float4*)(s_b + sub*16 + 8);
        float4 q3 = *(const float4*)(s_b + sub*16 + 12);
        #pragma unroll
        for (int it = 0; it < 8; ++it) {
            const int c = (it*16 + w)*4 + (lane >> 4);
            const uint4* wr = (const uint4*)(Wv2b + (long)c*C2) + sub*2;
            uint4 u0 = wr[0], u1 = wr[1];
            float2 p;
            float d = 0.f;
            p = bfpair(u0.x); d += p.x*q0.x + p.y*q0.y;
            p = bfpair(u0.y); d += p.x*q0.z + p.y*q0.w;
            p = bfpair(u0.z); d += p.x*q1.x + p.y*q1.y;
            p = bfpair(u0.w); d += p.x*q1.z + p.y*q1.w;
            p = bfpair(u1.x); d += p.x*q2.x + p.y*q2.y;
            p = bfpair(u1.y); d += p.x*q2.z + p.y*q2.w;
            p = bfpair(u1.z); d += p.x*q3.x + p.y*q3.y;
            p = bfpair(u1.w); d += p.x*q3.z + p.y*q3.w;
            #pragma unroll
            for (int off = 8; off; off >>= 1) d += __shfl_xor(d, off);
            if (sub == 0) veff[b*CC + c] = s_c[c] * d;
        }
    }
}

// ---------- K3: out = sigmoid(x.veff + constb) * cw * x  — 8 rows/block, 2 rows/wave
__global__ __launch_bounds__(256) void k_final(const float* __restrict__ x,
        const float* __restrict__ cw, const float* __restrict__ veff,
        const float* __restrict__ constb, float* __restrict__ out)
{
    const int lane = threadIdx.x & 63;
    const int wv   = threadIdx.x >> 6;
    const long row0 = (long)blockIdx.x * 8 + wv*2;        // rows row0, row0+1 (same b)
    const int b = (int)(row0 >> 12);
    const float* vb = veff + b*CC;
    float4 v0 = *(const float4*)(vb + lane*4);
    float4 v1 = *(const float4*)(vb + 256 + lane*4);
    const float* cb = cw + b*CC;
    float4 c0 = *(const float4*)(cb + lane*4);
    float4 c1 = *(const float4*)(cb + 256 + lane*4);
    const float* xr0 = x + row0 * CC;
    float4 a0 = *(const float4*)(xr0 + lane*4);
    float4 a1 = *(const float4*)(xr0 + 256 + lane*4);
    float4 b0 = *(const float4*)(xr0 + CC + lane*4);
    float4 b1 = *(const float4*)(xr0 + CC + 256 + lane*4);
    float d0 = dot8_(a0, a1, v0, v1);
    float d1 = dot8_(b0, b1, v0, v1);
    #pragma unroll
    for (int off = 32; off; off >>= 1) {
        d0 += __shfl_xor(d0, off);
        d1 += __shfl_xor(d1, off);
    }
    const float cbb = constb[b];
    const float sw0 = sigmoidf_(d0 + cbb);
    const float sw1 = sigmoidf_(d1 + cbb);
    f4v o0 = { sw0*c0.x*a0.x, sw0*c0.y*a0.y, sw0*c0.z*a0.z, sw0*c0.w*a0.w };
    f4v o1 = { sw0*c1.x*a1.x, sw0*c1.y*a1.y, sw0*c1.z*a1.z, sw0*c1.w*a1.w };
    f4v o2 = { sw1*c0.x*b0.x, sw1*c0.y*b0.y, sw1*c0.z*b0.z, sw1*c0.w*b0.w };
    f4v o3 = { sw1*c1.x*b1.x, sw1*c1.y*b1.y, sw1*c1.z*b1.z, sw1*c1.w*b1.w };
    __builtin_nontemporal_store(o0, (f4v*)(out + row0*CC + lane*4));
    __builtin_nontemporal_store(o1, (f4v*)(out + row0*CC + 256 + lane*4));
    __builtin_nontemporal_store(o2, (f4v*)(out + row0*CC + CC + lane*4));
    __builtin_nontemporal_store(o3, (f4v*)(out + row0*CC + CC + 256 + lane*4));
}

extern "C" void kernel_launch(void* const* d_in, const int* in_sizes, int n_in,
                              void* d_out, int out_size, void* d_ws, size_t ws_size,
                              hipStream_t stream)
{
    const float* x       = (const float*)d_in[0];
    const float* ch_wv_w = (const float*)d_in[1];
    const float* ch_wv_b = (const float*)d_in[2];
    const float* ch_wq_w = (const float*)d_in[3];
    // d_in[4] = ch_wq_b unused (softmax shift-invariant)
    const float* ch_wz_w = (const float*)d_in[5];
    const float* ch_wz_b = (const float*)d_in[6];
    const float* ln_g    = (const float*)d_in[7];
    const float* ln_b    = (const float*)d_in[8];
    const float* sp_wv_w = (const float*)d_in[9];
    const float* sp_wv_b = (const float*)d_in[10];
    const float* sp_wq_w = (const float*)d_in[11];
    const float* sp_wq_b = (const float*)d_in[12];
    float* out = (float*)d_out;

    float* ws = (float*)d_ws;
    float* part_w  = ws;                           // 16*64*512
    float* part_g  = part_w + BB*CHUNKS*CC;
    float* part_d  = part_g + BB*CHUNKS*CC;        // 1024
    float* cw      = part_d + BB*CHUNKS;           // 8192
    float* veff    = cw + BB*CC;                   // 8192
    float* constb  = veff + BB*CC;                 // 16
    ushort* wbf    = (ushort*)(constb + BB);       // 4*131072 bf16 = 1 MiB

    k_stats<<<BB*CHUNKS + 64, 256, 0, stream>>>(x, ch_wq_w,
                                                ch_wv_w, ch_wz_w, sp_wq_w, sp_wv_w,
                                                part_w, part_g, part_d, wbf);
    k_chain<<<BB, 1024, 0, stream>>>(part_w, part_g, part_d, wbf,
                                     ch_wv_b, ch_wz_b, ln_g, ln_b, sp_wq_b, sp_wv_b,
                                     cw, veff, constb);
    k_final<<<BB*NN/8, 256, 0, stream>>>(x, cw, veff, constb, out);
}